// Round 14
// baseline (282.924 us; speedup 1.0000x reference)
//
#include <hip/hip_runtime.h>

#define NVV 50000
#define NCC 50000
#define DD 128
#define FIN 32
#define INDIM 288
#define DEG 16

typedef unsigned short u16;
typedef unsigned char u8;
typedef unsigned int u32;
typedef __attribute__((ext_vector_type(8))) short short8;
typedef __attribute__((ext_vector_type(4))) float f32x4;
typedef __attribute__((ext_vector_type(2))) float f32x2;

constexpr int NT = 256;
constexpr int GRID_HALF = 782;   // ceil(50000/64)

__device__ __forceinline__ float b2f(u16 b) {
  union { u32 u; float f; } v; v.u = ((u32)b) << 16; return v.f;
}
__device__ __forceinline__ u16 f2b(float f) {
  union { float f; u32 u; } v; v.f = f;
  u32 u = v.u + 0x7FFFu + ((v.u >> 16) & 1u);
  return (u16)(u >> 16);
}
__device__ __forceinline__ float bits2f(u32 u) {
  union { u32 u; float f; } v; v.u = u; return v.f;
}
__device__ __forceinline__ u32 pack2(float a, float b) {
  return (u32)f2b(a) | ((u32)f2b(b) << 16);
}
__device__ __forceinline__ u8 f2fp8(float f) {
  return (u8)(__builtin_amdgcn_cvt_pk_fp8_f32(f, f, 0, false) & 0xFF);
}

// async 16B global->LDS DMA: per-lane global addr, LDS dest = base + lane*16
__device__ __forceinline__ void dma16(const void* g, void* l) {
  __builtin_amdgcn_global_load_lds(
      (__attribute__((address_space(1))) void*)g,
      (__attribute__((address_space(3))) void*)l, 16, 0, 0);
}

// dequant 8 consecutive fp8 (two u32) -> bf16x8 MFMA A-frag chunk (exact: e4m3 subset of bf16)
__device__ __forceinline__ short8 fp8x8_to_bf16frag(u32 lo, u32 hi) {
  f32x2 a0 = __builtin_amdgcn_cvt_pk_f32_fp8(lo, false);
  f32x2 a1 = __builtin_amdgcn_cvt_pk_f32_fp8(lo, true);
  f32x2 a2 = __builtin_amdgcn_cvt_pk_f32_fp8(hi, false);
  f32x2 a3 = __builtin_amdgcn_cvt_pk_f32_fp8(hi, true);
  u32 ab[4] = { pack2(a0.x, a0.y), pack2(a1.x, a1.y),
                pack2(a2.x, a2.y), pack2(a3.x, a3.y) };
  return *(short8*)ab;
}

// -------- weights fp32 -> bf16 MFMA B-fragment order + g zeroing --------
__global__ __launch_bounds__(NT) void swizzle_all(
    const float* __restrict__ Wv, const float* __restrict__ Wc,
    const float* __restrict__ Wiv, const float* __restrict__ Wic,
    u16* __restrict__ Wvsw, u16* __restrict__ Wcsw,
    u16* __restrict__ Wivsw, u16* __restrict__ Wicsw, float* __restrict__ g)
{
  int t = blockIdx.x * NT + threadIdx.x;
  if (t >= 10240) {
    int gi = t - 10240;
    if (gi < 128) g[gi] = 0.f;
    return;
  }
  const float* W; u16* out; int f; int indim;
  if (t < 4608)       { W = Wv;  out = Wvsw;  f = t;        indim = INDIM; }
  else if (t < 9216)  { W = Wc;  out = Wcsw;  f = t - 4608; indim = INDIM; }
  else if (t < 9728)  { W = Wiv; out = Wivsw; f = t - 9216; indim = FIN; }
  else                { W = Wic; out = Wicsw; f = t - 9728; indim = FIN; }
  int lane = f & 63, nt = (f >> 6) & 7, kt = f >> 9;
  int li = lane & 15, quad = lane >> 4;
  const float* src = W + (size_t)(nt * 16 + li) * indim + kt * 32 + quad * 8;
  float4 a = *(const float4*)src, b = *(const float4*)(src + 4);
  u32 o[4] = { pack2(a.x, a.y), pack2(a.z, a.w), pack2(b.x, b.y), pack2(b.z, b.w) };
  *(int4*)(out + (size_t)f * 8) = *(int4*)o;
}

// -------- init: fp8(x @ W^T + b) (staged coalesced) + bf16 feat --------
__global__ __launch_bounds__(NT) void init_fused(
    const float* __restrict__ x,
    const u16* __restrict__ Wivsw, const u16* __restrict__ Wicsw,
    const float* __restrict__ b_iv, const float* __restrict__ b_ic,
    u8* __restrict__ lv08, u8* __restrict__ lc08,
    u16* __restrict__ xvb, u16* __restrict__ xcb)
{
  __shared__ char smem8[4 * 2048];   // per-wave 2KB fp8 staging
  const int bid = blockIdx.x;
  const bool isC = bid >= GRID_HALF;
  const int lb = isC ? bid - GRID_HALF : bid;
  const float* xs = x + (isC ? (size_t)NVV * FIN : 0);
  const u16* Wsw = isC ? Wicsw : Wivsw;
  const float* bias = isC ? b_ic : b_iv;
  u8*  out8 = isC ? lc08 : lv08;
  u16* feat = isC ? xcb : xvb;
  const int nrows = isC ? NCC : NVV;

  const int t = threadIdx.x;
  const int r0 = lb * 64;

  {
    const int row = r0 + (t >> 2);
    if (row < nrows) {
      const float* src = xs + (size_t)row * FIN + (t & 3) * 8;
      float4 a = *(const float4*)src, b = *(const float4*)(src + 4);
      u32 o[4] = { pack2(a.x, a.y), pack2(a.z, a.w), pack2(b.x, b.y), pack2(b.z, b.w) };
      *(int4*)(feat + (size_t)row * FIN + (t & 3) * 8) = *(int4*)o;
    }
  }

  const int wave = t >> 6, l = t & 63;
  const int quad = l >> 4, li = l & 15;
  const int r0w = r0 + wave * 16;
  int rowm = r0w + li;
  if (rowm >= nrows) rowm = nrows - 1;

  short8 afrag;
  {
    const float* src = xs + (size_t)rowm * FIN + quad * 8;
    float4 a = *(const float4*)src, b = *(const float4*)(src + 4);
    u32 o[4] = { pack2(a.x, a.y), pack2(a.z, a.w), pack2(b.x, b.y), pack2(b.z, b.w) };
    afrag = *(short8*)o;
  }

  f32x4 acc[8];
#pragma unroll
  for (int nt = 0; nt < 8; ++nt) acc[nt] = (f32x4){0.f, 0.f, 0.f, 0.f};
#pragma unroll
  for (int nt = 0; nt < 8; ++nt) {
    short8 b = *(const short8*)(Wsw + (size_t)(nt * 64 + l) * 8);
    acc[nt] = __builtin_amdgcn_mfma_f32_16x16x32_bf16(afrag, b, acc[nt], 0, 0, 0);
  }

  u8* s8 = (u8*)(smem8 + wave * 2048);
#pragma unroll
  for (int nt = 0; nt < 8; ++nt) {
    const int col = nt * 16 + li;
    const float bv = bias[col];
#pragma unroll
    for (int i = 0; i < 4; ++i)
      s8[(quad * 4 + i) * 128 + col] = f2fp8(acc[nt][i] + bv);
  }
  asm volatile("s_waitcnt lgkmcnt(0)" ::: "memory");
  if (r0w < nrows) {   // nrows % 16 == 0 -> whole-wave validity
    const char* s8c = (const char*)s8 + l * 32;
    char* g8 = (char*)out8 + (size_t)r0w * 128 + l * 32;
#pragma unroll
    for (int c = 0; c < 2; ++c) *(int4*)(g8 + c * 16) = *(const int4*)(s8c + c * 16);
  }
}

// ---- fp8 gather ring helpers ----
__device__ __forceinline__ void issue_group8(const char* gp, int offj, char* slotbase) {
  const char* rp = gp + (size_t)(u32)offj;
  dma16(rp, slotbase);
  dma16(rp + 64, slotbase + 1024);
}
__device__ __forceinline__ void consume_slot8(const char* slot, int li, int quad,
                                              float (&sagg)[4][8]) {
  const int c2 = quad >> 1, half = quad & 1;
#pragma unroll
  for (int kt = 0; kt < 4; ++kt) {
    int4 v = *(const int4*)(slot + (2 * kt + c2) * 256 + li * 16);
    u32 w0 = half ? (u32)v.z : (u32)v.x;
    u32 w1 = half ? (u32)v.w : (u32)v.y;
    f32x2 a0 = __builtin_amdgcn_cvt_pk_f32_fp8(w0, false);
    f32x2 a1 = __builtin_amdgcn_cvt_pk_f32_fp8(w0, true);
    f32x2 a2 = __builtin_amdgcn_cvt_pk_f32_fp8(w1, false);
    f32x2 a3 = __builtin_amdgcn_cvt_pk_f32_fp8(w1, true);
    sagg[kt][0] += a0.x; sagg[kt][1] += a0.y;
    sagg[kt][2] += a1.x; sagg[kt][3] += a1.y;
    sagg[kt][4] += a2.x; sagg[kt][5] += a2.y;
    sagg[kt][6] += a3.x; sagg[kt][7] += a3.y;
  }
}

// ------------- fused layer body: ring issued BEFORE dense tiles (latency overlap) -------------
template <bool GACC>
__device__ __forceinline__ void layer_body(
    const u8* __restrict__ gsrc, const u8* __restrict__ self8,
    const u16* __restrict__ feat, const int* __restrict__ idx,
    const u16* __restrict__ Wsw, const float* __restrict__ bias,
    u16* __restrict__ out16, u8* __restrict__ out8, float* __restrict__ g,
    int nrows, int bid, int t, char* smem)
{
  const int wave = t >> 6, l = t & 63;
  const int quad = l >> 4, li = l & 15;
  const int r0w = bid * 64 + wave * 16;

  int4 iv;
  {
    int rload = r0w + (l >> 2);
    if (rload >= nrows) rload = nrows - 1;
    iv = *(const int4*)(idx + (size_t)rload * DEG + (l & 3) * 4);
  }
  int off[DEG];
#pragma unroll
  for (int j = 0; j < DEG; ++j) {
    int comp = ((j & 3) == 0) ? iv.x : ((j & 3) == 1) ? iv.y : ((j & 3) == 2) ? iv.z : iv.w;
    off[j] = __shfl(comp, (li << 2) + (j >> 2)) << 7;   // * 128 B per fp8 row
  }

  int rowm = r0w + li;
  if (rowm >= nrows) rowm = nrows - 1;

  // ---- issue first 4 ring slots NOW; their latency hides under the dense tiles.
  // FIFO vmcnt semantics: dense loads are younger, so compiler waits for dense
  // loads also drain these older DMAs -> vmcnt(6) in the ring stays correct.
  char* wb = smem + wave * 8192;               // 4 slots x 2KB
  const char* gp = (const char*)gsrc + quad * 16;
  asm volatile("s_waitcnt vmcnt(0)" ::: "memory");  // FIFO = ours only (idx load done)
  issue_group8(gp, off[0], wb);
  issue_group8(gp, off[1], wb + 2048);
  issue_group8(gp, off[2], wb + 4096);
  issue_group8(gp, off[3], wb + 6144);

  f32x4 acc[8];
#pragma unroll
  for (int nt = 0; nt < 8; ++nt) acc[nt] = (f32x4){0.f, 0.f, 0.f, 0.f};

  // ---- dense tiles (overlap with in-flight slot DMAs) ----
  {
    short8 a = *(const short8*)(feat + (size_t)rowm * FIN + quad * 8);
#pragma unroll
    for (int nt = 0; nt < 8; ++nt) {
      short8 b = *(const short8*)(Wsw + (size_t)((8 * 8 + nt) * 64 + l) * 8);
      acc[nt] = __builtin_amdgcn_mfma_f32_16x16x32_bf16(a, b, acc[nt], 0, 0, 0);
    }
  }
#pragma unroll
  for (int k2 = 0; k2 < 4; ++k2) {
    const u32* sp = (const u32*)(self8 + (size_t)rowm * DD + k2 * 32 + quad * 8);
    short8 a = fp8x8_to_bf16frag(sp[0], sp[1]);
#pragma unroll
    for (int nt = 0; nt < 8; ++nt) {
      short8 b = *(const short8*)(Wsw + (size_t)(((4 + k2) * 8 + nt) * 64 + l) * 8);
      acc[nt] = __builtin_amdgcn_mfma_f32_16x16x32_bf16(a, b, acc[nt], 0, 0, 0);
    }
  }

  // ---- fp8 gather ring (slots 0-3 already in flight / landed) ----
  float sagg[4][8];
#pragma unroll
  for (int k2 = 0; k2 < 4; ++k2)
#pragma unroll
    for (int p = 0; p < 8; ++p) sagg[k2][p] = 0.f;

#define R8_STEP(J, IJ)                                               \
  asm volatile("s_waitcnt vmcnt(6)" ::: "memory");                   \
  consume_slot8(wb + ((J) & 3) * 2048, li, quad, sagg);              \
  asm volatile("s_waitcnt lgkmcnt(0)" ::: "memory");                 \
  issue_group8(gp, off[IJ], wb + ((J) & 3) * 2048);
#define R8_TAIL(J, VN)                                               \
  asm volatile("s_waitcnt vmcnt(" #VN ")" ::: "memory");             \
  consume_slot8(wb + ((J) & 3) * 2048, li, quad, sagg);
  R8_STEP(0, 4)  R8_STEP(1, 5)  R8_STEP(2, 6)  R8_STEP(3, 7)
  R8_STEP(4, 8)  R8_STEP(5, 9)  R8_STEP(6, 10) R8_STEP(7, 11)
  R8_STEP(8, 12) R8_STEP(9, 13) R8_STEP(10, 14) R8_STEP(11, 15)
  R8_TAIL(12, 6) R8_TAIL(13, 4) R8_TAIL(14, 2)  R8_TAIL(15, 0)
#undef R8_STEP
#undef R8_TAIL

  // ---- gather-tile MFMAs (kt = 0..3) ----
#pragma unroll
  for (int k2 = 0; k2 < 4; ++k2) {
    u32 a_bits[4];
#pragma unroll
    for (int p = 0; p < 4; ++p) a_bits[p] = pack2(sagg[k2][2 * p], sagg[k2][2 * p + 1]);
    short8 a = *(short8*)a_bits;
#pragma unroll
    for (int nt = 0; nt < 8; ++nt) {
      short8 b = *(const short8*)(Wsw + (size_t)((k2 * 8 + nt) * 64 + l) * 8);
      acc[nt] = __builtin_amdgcn_mfma_f32_16x16x32_bf16(a, b, acc[nt], 0, 0, 0);
    }
  }

  // ---- epilogue ----
  asm volatile("s_waitcnt lgkmcnt(0)" ::: "memory");  // ring ds ops fully drained
  if constexpr (!GACC) {
    u8* s8 = (u8*)wb;
#pragma unroll
    for (int nt = 0; nt < 8; ++nt) {
      const int col = nt * 16 + li;
      const float bv = bias[col];
#pragma unroll
      for (int i = 0; i < 4; ++i)
        s8[(quad * 4 + i) * 128 + col] = f2fp8(acc[nt][i] + bv);
    }
    asm volatile("s_waitcnt lgkmcnt(0)" ::: "memory");
    if (r0w < nrows) {   // nrows % 16 == 0 -> whole-wave validity
      const char* s8c = (const char*)s8 + l * 32;
      char* g8 = (char*)out8 + (size_t)r0w * 128 + l * 32;
#pragma unroll
      for (int c = 0; c < 2; ++c) *(int4*)(g8 + c * 16) = *(const int4*)(s8c + c * 16);
    }
  } else {
    const int rbase = r0w + quad * 4;
    float colsum[8];
#pragma unroll
    for (int nt = 0; nt < 8; ++nt) {
      const int col = nt * 16 + li;
      const float bv = bias[col];
      colsum[nt] = 0.f;
#pragma unroll
      for (int i = 0; i < 4; ++i) {
        const int row = rbase + i;
        float v = acc[nt][i] + bv;
        if (row < nrows) {
          out16[(size_t)row * DD + col] = f2b(v);
          colsum[nt] += v;
        }
      }
    }
#pragma unroll
    for (int nt = 0; nt < 8; ++nt) {
      colsum[nt] += __shfl_xor(colsum[nt], 16);
      colsum[nt] += __shfl_xor(colsum[nt], 32);
    }
    __syncthreads();               // ring LDS dead everywhere; reuse
    float* gsum = (float*)smem;    // [4][128]
    if (quad == 0) {
#pragma unroll
      for (int nt = 0; nt < 8; ++nt) gsum[wave * 128 + nt * 16 + li] = colsum[nt];
    }
    __syncthreads();
    if (t < 128) {
      float tot = gsum[t] + gsum[128 + t] + gsum[256 + t] + gsum[384 + t];
      atomicAdd(&g[t], tot);
    }
  }
}

template <bool GACC>
__global__ __launch_bounds__(NT, 2) void layer_merged(
    const u8* gsrcC, const u8* selfC, const u16* featC, const int* idxC,
    const u16* WswC, const float* biasC, u16* out16C, u8* out8C, int nrowsC,
    const u8* gsrcV, const u8* selfV, const u16* featV, const int* idxV,
    const u16* WswV, const float* biasV, u16* out16V, u8* out8V, int nrowsV,
    float* g, int c_blocks)
{
  __shared__ char smem[32768];
  const int bid = blockIdx.x;
  const int t = threadIdx.x;
  if (bid < c_blocks)
    layer_body<GACC>(gsrcC, selfC, featC, idxC, WswC, biasC, out16C, out8C,
                     g, nrowsC, bid, t, smem);
  else
    layer_body<GACC>(gsrcV, selfV, featV, idxV, WswV, biasV, out16V, out8V,
                     g, nrowsV, bid - c_blocks, t, smem);
}

// ------------- Q[r] = b_q + dot(Wq[0:128], g) + dot(Wq[128:256], lv[r]) -------------
__global__ __launch_bounds__(NT) void final_kernel(
    const u16* __restrict__ lv, const float* __restrict__ g,
    const float* __restrict__ Wq, const float* __restrict__ bq,
    float* __restrict__ out)
{
  const int t = threadIdx.x, wave = t >> 6, l = t & 63;
  const float2 wg = *(const float2*)(Wq + 2 * l);
  const float2 wl = *(const float2*)(Wq + DD + 2 * l);
  const float2 gv = *(const float2*)(g + 2 * l);
  float q = wg.x * gv.x + wg.y * gv.y;
#pragma unroll
  for (int off = 32; off; off >>= 1) q += __shfl_down(q, off);
  const float qg = __shfl(q, 0) + bq[0];

  const int r0w = blockIdx.x * 64 + wave * 16;
#pragma unroll
  for (int i = 0; i < 16; ++i) {
    const int r = r0w + i;
    if (r >= NVV) break;
    u32 v = *(const u32*)(lv + (size_t)r * DD + 2 * l);
    float p = wl.x * b2f((u16)(v & 0xFFFF)) + wl.y * b2f((u16)(v >> 16));
#pragma unroll
    for (int off = 32; off; off >>= 1) p += __shfl_down(p, off);
    if (l == 0) out[r] = qg + p;
  }
}

extern "C" void kernel_launch(void* const* d_in, const int* in_sizes, int n_in,
                              void* d_out, int out_size, void* d_ws, size_t ws_size,
                              hipStream_t stream) {
  const float* x    = (const float*)d_in[0];
  const int*   vci  = (const int*)d_in[1];   // var_constr_index -> gathers from lc
  const int*   cvi  = (const int*)d_in[2];   // constr_var_index -> gathers from lv
  const float* W_iv = (const float*)d_in[3];
  const float* b_iv = (const float*)d_in[4];
  const float* W_ic = (const float*)d_in[5];
  const float* b_ic = (const float*)d_in[6];
  const float* W_v  = (const float*)d_in[7];
  const float* b_v  = (const float*)d_in[8];
  const float* W_c  = (const float*)d_in[9];
  const float* b_c  = (const float*)d_in[10];
  const float* W_q  = (const float*)d_in[11];
  const float* b_q  = (const float*)d_in[12];
  float* out = (float*)d_out;

  float* g = (float*)d_ws;
  u16* base = (u16*)((char*)d_ws + 512);
  const size_t nodef = (size_t)NVV * DD;
  u16* xb    = base;
  u16* Wvsw  = xb + (size_t)(NVV + NCC) * FIN;
  u16* Wcsw  = Wvsw + (size_t)DD * INDIM;
  u16* Wivsw = Wcsw + (size_t)DD * INDIM;
  u16* Wicsw = Wivsw + (size_t)DD * FIN;
  u16* lv1   = Wicsw + (size_t)DD * FIN;      // bf16 final lv (it2 output)
  u8*  lv08  = (u8*)(lv1 + nodef);            // fp8 gen0; dead after it0 -> reused as gen2
  u8*  lc08  = lv08 + nodef;
  u8*  lv18  = lc08 + nodef;
  u8*  lc18  = lv18 + nodef;
  u8*  lv28  = lv08;                          // alias gen2 onto gen0
  u8*  lc28  = lc08;
  u16* xvb   = xb;
  u16* xcb   = xb + (size_t)NVV * FIN;

  dim3 blk(NT);

  swizzle_all<<<41, blk, 0, stream>>>(W_v, W_c, W_iv, W_ic, Wvsw, Wcsw, Wivsw, Wicsw, g);
  init_fused<<<2 * GRID_HALF, blk, 0, stream>>>(x, Wivsw, Wicsw, b_iv, b_ic,
                                                lv08, lc08, xvb, xcb);

  // it0: C: gather lv08, self lc08 -> lc18 ; V: gather lc08, self lv08 -> lv18
  layer_merged<false><<<2 * GRID_HALF, blk, 0, stream>>>(
      lv08, lc08, xcb, cvi, Wcsw, b_c, nullptr, lc18, NCC,
      lc08, lv08, xvb, vci, Wvsw, b_v, nullptr, lv18, NVV, g, GRID_HALF);
  // it1: C: gather lv18, self lc18 -> lc28 ; V: gather lc18, self lv18 -> lv28
  layer_merged<false><<<2 * GRID_HALF, blk, 0, stream>>>(
      lv18, lc18, xcb, cvi, Wcsw, b_c, nullptr, lc28, NCC,
      lc18, lv18, xvb, vci, Wvsw, b_v, nullptr, lv28, NVV, g, GRID_HALF);
  // it2: V only: gather lc28, self lv28 -> lv1 (bf16) + g
  layer_merged<true><<<GRID_HALF, blk, 0, stream>>>(
      lc28, lv28, xvb, vci, Wvsw, b_v, lv1, nullptr, NVV,  // unused C slot
      lc28, lv28, xvb, vci, Wvsw, b_v, lv1, nullptr, NVV, g, 0);

  final_kernel<<<GRID_HALF, blk, 0, stream>>>(lv1, g, W_q, b_q, out);
}

// Round 15
// 278.843 us; speedup vs baseline: 1.0146x; 1.0146x over previous
//
#include <hip/hip_runtime.h>

#define NVV 50000
#define NCC 50000
#define DD 128
#define FIN 32
#define INDIM 288
#define DEG 16

typedef unsigned short u16;
typedef unsigned char u8;
typedef unsigned int u32;
typedef __attribute__((ext_vector_type(8))) short short8;
typedef __attribute__((ext_vector_type(4))) float f32x4;
typedef __attribute__((ext_vector_type(2))) float f32x2;

constexpr int NT = 256;
constexpr int GRID_HALF = 782;   // ceil(50000/64)

__device__ __forceinline__ float b2f(u16 b) {
  union { u32 u; float f; } v; v.u = ((u32)b) << 16; return v.f;
}
__device__ __forceinline__ u16 f2b(float f) {
  union { float f; u32 u; } v; v.f = f;
  u32 u = v.u + 0x7FFFu + ((v.u >> 16) & 1u);
  return (u16)(u >> 16);
}
__device__ __forceinline__ u32 pack2(float a, float b) {
  return (u32)f2b(a) | ((u32)f2b(b) << 16);
}
__device__ __forceinline__ u8 f2fp8(float f) {
  return (u8)(__builtin_amdgcn_cvt_pk_fp8_f32(f, f, 0, false) & 0xFF);
}

// async 16B global->LDS DMA: per-lane global addr, LDS dest = base + lane*16
__device__ __forceinline__ void dma16(const void* g, void* l) {
  __builtin_amdgcn_global_load_lds(
      (__attribute__((address_space(1))) void*)g,
      (__attribute__((address_space(3))) void*)l, 16, 0, 0);
}

// dequant 8 consecutive fp8 (two u32) -> bf16x8 MFMA A-frag chunk (exact: e4m3 subset of bf16)
__device__ __forceinline__ short8 fp8x8_to_bf16frag(u32 lo, u32 hi) {
  f32x2 a0 = __builtin_amdgcn_cvt_pk_f32_fp8(lo, false);
  f32x2 a1 = __builtin_amdgcn_cvt_pk_f32_fp8(lo, true);
  f32x2 a2 = __builtin_amdgcn_cvt_pk_f32_fp8(hi, false);
  f32x2 a3 = __builtin_amdgcn_cvt_pk_f32_fp8(hi, true);
  u32 ab[4] = { pack2(a0.x, a0.y), pack2(a1.x, a1.y),
                pack2(a2.x, a2.y), pack2(a3.x, a3.y) };
  return *(short8*)ab;
}
// pack 8 floats (two float4) -> 8 fp8 bytes (two u32)
__device__ __forceinline__ void f32x8_to_fp8x8(float4 a, float4 b, u32* o) {
  u32 lo = 0, hi = 0;
  lo = __builtin_amdgcn_cvt_pk_fp8_f32(a.x, a.y, lo, false);
  lo = __builtin_amdgcn_cvt_pk_fp8_f32(a.z, a.w, lo, true);
  hi = __builtin_amdgcn_cvt_pk_fp8_f32(b.x, b.y, hi, false);
  hi = __builtin_amdgcn_cvt_pk_fp8_f32(b.z, b.w, hi, true);
  o[0] = lo; o[1] = hi;
}

// -------- weights fp32 -> bf16 MFMA B-fragment order + g zeroing --------
__global__ __launch_bounds__(NT) void swizzle_all(
    const float* __restrict__ Wv, const float* __restrict__ Wc,
    const float* __restrict__ Wiv, const float* __restrict__ Wic,
    u16* __restrict__ Wvsw, u16* __restrict__ Wcsw,
    u16* __restrict__ Wivsw, u16* __restrict__ Wicsw, float* __restrict__ g)
{
  int t = blockIdx.x * NT + threadIdx.x;
  if (t >= 10240) {
    int gi = t - 10240;
    if (gi < 128) g[gi] = 0.f;
    return;
  }
  const float* W; u16* out; int f; int indim;
  if (t < 4608)       { W = Wv;  out = Wvsw;  f = t;        indim = INDIM; }
  else if (t < 9216)  { W = Wc;  out = Wcsw;  f = t - 4608; indim = INDIM; }
  else if (t < 9728)  { W = Wiv; out = Wivsw; f = t - 9216; indim = FIN; }
  else                { W = Wic; out = Wicsw; f = t - 9728; indim = FIN; }
  int lane = f & 63, nt = (f >> 6) & 7, kt = f >> 9;
  int li = lane & 15, quad = lane >> 4;
  const float* src = W + (size_t)(nt * 16 + li) * indim + kt * 32 + quad * 8;
  float4 a = *(const float4*)src, b = *(const float4*)(src + 4);
  u32 o[4] = { pack2(a.x, a.y), pack2(a.z, a.w), pack2(b.x, b.y), pack2(b.z, b.w) };
  *(int4*)(out + (size_t)f * 8) = *(int4*)o;
}

// -------- init: fp8(x @ W^T + b) (staged coalesced) + fp8 feat --------
__global__ __launch_bounds__(NT) void init_fused(
    const float* __restrict__ x,
    const u16* __restrict__ Wivsw, const u16* __restrict__ Wicsw,
    const float* __restrict__ b_iv, const float* __restrict__ b_ic,
    u8* __restrict__ lv08, u8* __restrict__ lc08,
    u8* __restrict__ xvb8, u8* __restrict__ xcb8)
{
  __shared__ char smem8[4 * 2048];   // per-wave 2KB fp8 staging
  const int bid = blockIdx.x;
  const bool isC = bid >= GRID_HALF;
  const int lb = isC ? bid - GRID_HALF : bid;
  const float* xs = x + (isC ? (size_t)NVV * FIN : 0);
  const u16* Wsw = isC ? Wicsw : Wivsw;
  const float* bias = isC ? b_ic : b_iv;
  u8*  out8 = isC ? lc08 : lv08;
  u8*  feat8 = isC ? xcb8 : xvb8;
  const int nrows = isC ? NCC : NVV;

  const int t = threadIdx.x;
  const int r0 = lb * 64;

  {  // feat fp8 convert+store: thread t -> row r0+(t>>2), cols (t&3)*8..+7 (8B store)
    const int row = r0 + (t >> 2);
    if (row < nrows) {
      const float* src = xs + (size_t)row * FIN + (t & 3) * 8;
      u32 o[2];
      f32x8_to_fp8x8(*(const float4*)src, *(const float4*)(src + 4), o);
      *(int2*)(feat8 + (size_t)row * FIN + (t & 3) * 8) = *(int2*)o;
    }
  }

  const int wave = t >> 6, l = t & 63;
  const int quad = l >> 4, li = l & 15;
  const int r0w = r0 + wave * 16;
  int rowm = r0w + li;
  if (rowm >= nrows) rowm = nrows - 1;

  short8 afrag;
  {
    const float* src = xs + (size_t)rowm * FIN + quad * 8;
    float4 a = *(const float4*)src, b = *(const float4*)(src + 4);
    u32 o[4] = { pack2(a.x, a.y), pack2(a.z, a.w), pack2(b.x, b.y), pack2(b.z, b.w) };
    afrag = *(short8*)o;
  }

  f32x4 acc[8];
#pragma unroll
  for (int nt = 0; nt < 8; ++nt) acc[nt] = (f32x4){0.f, 0.f, 0.f, 0.f};
#pragma unroll
  for (int nt = 0; nt < 8; ++nt) {
    short8 b = *(const short8*)(Wsw + (size_t)(nt * 64 + l) * 8);
    acc[nt] = __builtin_amdgcn_mfma_f32_16x16x32_bf16(afrag, b, acc[nt], 0, 0, 0);
  }

  u8* s8 = (u8*)(smem8 + wave * 2048);
#pragma unroll
  for (int nt = 0; nt < 8; ++nt) {
    const int col = nt * 16 + li;
    const float bv = bias[col];
#pragma unroll
    for (int i = 0; i < 4; ++i)
      s8[(quad * 4 + i) * 128 + col] = f2fp8(acc[nt][i] + bv);
  }
  asm volatile("s_waitcnt lgkmcnt(0)" ::: "memory");
  if (r0w < nrows) {   // nrows % 16 == 0 -> whole-wave validity
    const char* s8c = (const char*)s8 + l * 32;
    char* g8 = (char*)out8 + (size_t)r0w * 128 + l * 32;
#pragma unroll
    for (int c = 0; c < 2; ++c) *(int4*)(g8 + c * 16) = *(const int4*)(s8c + c * 16);
  }
}

// ---- fp8 gather ring helpers ----
__device__ __forceinline__ void issue_group8(const char* gp, int offj, char* slotbase) {
  const char* rp = gp + (size_t)(u32)offj;
  dma16(rp, slotbase);
  dma16(rp + 64, slotbase + 1024);
}
__device__ __forceinline__ void consume_slot8(const char* slot, int li, int quad,
                                              float (&sagg)[4][8]) {
  const int c2 = quad >> 1, half = quad & 1;
#pragma unroll
  for (int kt = 0; kt < 4; ++kt) {
    int4 v = *(const int4*)(slot + (2 * kt + c2) * 256 + li * 16);
    u32 w0 = half ? (u32)v.z : (u32)v.x;
    u32 w1 = half ? (u32)v.w : (u32)v.y;
    f32x2 a0 = __builtin_amdgcn_cvt_pk_f32_fp8(w0, false);
    f32x2 a1 = __builtin_amdgcn_cvt_pk_f32_fp8(w0, true);
    f32x2 a2 = __builtin_amdgcn_cvt_pk_f32_fp8(w1, false);
    f32x2 a3 = __builtin_amdgcn_cvt_pk_f32_fp8(w1, true);
    sagg[kt][0] += a0.x; sagg[kt][1] += a0.y;
    sagg[kt][2] += a1.x; sagg[kt][3] += a1.y;
    sagg[kt][4] += a2.x; sagg[kt][5] += a2.y;
    sagg[kt][6] += a3.x; sagg[kt][7] += a3.y;
  }
}

// ------------- fused layer body: ring issued BEFORE dense tiles (latency overlap) -------------
template <bool GACC>
__device__ __forceinline__ void layer_body(
    const u8* __restrict__ gsrc, const u8* __restrict__ self8,
    const u8* __restrict__ feat8, const int* __restrict__ idx,
    const u16* __restrict__ Wsw, const float* __restrict__ bias,
    u16* __restrict__ out16, u8* __restrict__ out8, float* __restrict__ g,
    int nrows, int bid, int t, char* smem)
{
  const int wave = t >> 6, l = t & 63;
  const int quad = l >> 4, li = l & 15;
  const int r0w = bid * 64 + wave * 16;

  int4 iv;
  {
    int rload = r0w + (l >> 2);
    if (rload >= nrows) rload = nrows - 1;
    iv = *(const int4*)(idx + (size_t)rload * DEG + (l & 3) * 4);
  }
  int off[DEG];
#pragma unroll
  for (int j = 0; j < DEG; ++j) {
    int comp = ((j & 3) == 0) ? iv.x : ((j & 3) == 1) ? iv.y : ((j & 3) == 2) ? iv.z : iv.w;
    off[j] = __shfl(comp, (li << 2) + (j >> 2)) << 7;   // * 128 B per fp8 row
  }

  int rowm = r0w + li;
  if (rowm >= nrows) rowm = nrows - 1;

  // ---- issue first 4 ring slots NOW; latency hides under the dense tiles.
  char* wb = smem + wave * 8192;               // 4 slots x 2KB
  const char* gp = (const char*)gsrc + quad * 16;
  asm volatile("s_waitcnt vmcnt(0)" ::: "memory");  // FIFO = ours only (idx load done)
  issue_group8(gp, off[0], wb);
  issue_group8(gp, off[1], wb + 2048);
  issue_group8(gp, off[2], wb + 4096);
  issue_group8(gp, off[3], wb + 6144);

  f32x4 acc[8];
#pragma unroll
  for (int nt = 0; nt < 8; ++nt) acc[nt] = (f32x4){0.f, 0.f, 0.f, 0.f};

  // ---- dense tiles (overlap with in-flight slot DMAs) ----
  {
    const u32* fp = (const u32*)(feat8 + (size_t)rowm * FIN + quad * 8);
    short8 a = fp8x8_to_bf16frag(fp[0], fp[1]);
#pragma unroll
    for (int nt = 0; nt < 8; ++nt) {
      short8 b = *(const short8*)(Wsw + (size_t)((8 * 8 + nt) * 64 + l) * 8);
      acc[nt] = __builtin_amdgcn_mfma_f32_16x16x32_bf16(a, b, acc[nt], 0, 0, 0);
    }
  }
#pragma unroll
  for (int k2 = 0; k2 < 4; ++k2) {
    const u32* sp = (const u32*)(self8 + (size_t)rowm * DD + k2 * 32 + quad * 8);
    short8 a = fp8x8_to_bf16frag(sp[0], sp[1]);
#pragma unroll
    for (int nt = 0; nt < 8; ++nt) {
      short8 b = *(const short8*)(Wsw + (size_t)(((4 + k2) * 8 + nt) * 64 + l) * 8);
      acc[nt] = __builtin_amdgcn_mfma_f32_16x16x32_bf16(a, b, acc[nt], 0, 0, 0);
    }
  }

  // ---- fp8 gather ring (slots 0-3 already in flight / landed) ----
  float sagg[4][8];
#pragma unroll
  for (int k2 = 0; k2 < 4; ++k2)
#pragma unroll
    for (int p = 0; p < 8; ++p) sagg[k2][p] = 0.f;

#define R8_STEP(J, IJ)                                               \
  asm volatile("s_waitcnt vmcnt(6)" ::: "memory");                   \
  consume_slot8(wb + ((J) & 3) * 2048, li, quad, sagg);              \
  asm volatile("s_waitcnt lgkmcnt(0)" ::: "memory");                 \
  issue_group8(gp, off[IJ], wb + ((J) & 3) * 2048);
#define R8_TAIL(J, VN)                                               \
  asm volatile("s_waitcnt vmcnt(" #VN ")" ::: "memory");             \
  consume_slot8(wb + ((J) & 3) * 2048, li, quad, sagg);
  R8_STEP(0, 4)  R8_STEP(1, 5)  R8_STEP(2, 6)  R8_STEP(3, 7)
  R8_STEP(4, 8)  R8_STEP(5, 9)  R8_STEP(6, 10) R8_STEP(7, 11)
  R8_STEP(8, 12) R8_STEP(9, 13) R8_STEP(10, 14) R8_STEP(11, 15)
  R8_TAIL(12, 6) R8_TAIL(13, 4) R8_TAIL(14, 2)  R8_TAIL(15, 0)
#undef R8_STEP
#undef R8_TAIL

  // ---- gather-tile MFMAs (kt = 0..3) ----
#pragma unroll
  for (int k2 = 0; k2 < 4; ++k2) {
    u32 a_bits[4];
#pragma unroll
    for (int p = 0; p < 4; ++p) a_bits[p] = pack2(sagg[k2][2 * p], sagg[k2][2 * p + 1]);
    short8 a = *(short8*)a_bits;
#pragma unroll
    for (int nt = 0; nt < 8; ++nt) {
      short8 b = *(const short8*)(Wsw + (size_t)((k2 * 8 + nt) * 64 + l) * 8);
      acc[nt] = __builtin_amdgcn_mfma_f32_16x16x32_bf16(a, b, acc[nt], 0, 0, 0);
    }
  }

  // ---- epilogue ----
  asm volatile("s_waitcnt lgkmcnt(0)" ::: "memory");  // ring ds ops fully drained
  if constexpr (!GACC) {
    u8* s8 = (u8*)wb;
#pragma unroll
    for (int nt = 0; nt < 8; ++nt) {
      const int col = nt * 16 + li;
      const float bv = bias[col];
#pragma unroll
      for (int i = 0; i < 4; ++i)
        s8[(quad * 4 + i) * 128 + col] = f2fp8(acc[nt][i] + bv);
    }
    asm volatile("s_waitcnt lgkmcnt(0)" ::: "memory");
    if (r0w < nrows) {   // nrows % 16 == 0 -> whole-wave validity
      const char* s8c = (const char*)s8 + l * 32;
      char* g8 = (char*)out8 + (size_t)r0w * 128 + l * 32;
#pragma unroll
      for (int c = 0; c < 2; ++c) *(int4*)(g8 + c * 16) = *(const int4*)(s8c + c * 16);
    }
  } else {
    const int rbase = r0w + quad * 4;
    float colsum[8];
#pragma unroll
    for (int nt = 0; nt < 8; ++nt) {
      const int col = nt * 16 + li;
      const float bv = bias[col];
      colsum[nt] = 0.f;
#pragma unroll
      for (int i = 0; i < 4; ++i) {
        const int row = rbase + i;
        float v = acc[nt][i] + bv;
        if (row < nrows) {
          out16[(size_t)row * DD + col] = f2b(v);
          colsum[nt] += v;
        }
      }
    }
#pragma unroll
    for (int nt = 0; nt < 8; ++nt) {
      colsum[nt] += __shfl_xor(colsum[nt], 16);
      colsum[nt] += __shfl_xor(colsum[nt], 32);
    }
    __syncthreads();               // ring LDS dead everywhere; reuse
    float* gsum = (float*)smem;    // [4][128]
    if (quad == 0) {
#pragma unroll
      for (int nt = 0; nt < 8; ++nt) gsum[wave * 128 + nt * 16 + li] = colsum[nt];
    }
    __syncthreads();
    if (t < 128) {
      float tot = gsum[t] + gsum[128 + t] + gsum[256 + t] + gsum[384 + t];
      atomicAdd(&g[t], tot);
    }
  }
}

template <bool GACC>
__global__ __launch_bounds__(NT, 2) void layer_merged(
    const u8* gsrcC, const u8* selfC, const u8* featC, const int* idxC,
    const u16* WswC, const float* biasC, u16* out16C, u8* out8C, int nrowsC,
    const u8* gsrcV, const u8* selfV, const u8* featV, const int* idxV,
    const u16* WswV, const float* biasV, u16* out16V, u8* out8V, int nrowsV,
    float* g, int c_blocks)
{
  __shared__ char smem[32768];
  const int bid = blockIdx.x;
  const int t = threadIdx.x;
  if (bid < c_blocks)
    layer_body<GACC>(gsrcC, selfC, featC, idxC, WswC, biasC, out16C, out8C,
                     g, nrowsC, bid, t, smem);
  else
    layer_body<GACC>(gsrcV, selfV, featV, idxV, WswV, biasV, out16V, out8V,
                     g, nrowsV, bid - c_blocks, t, smem);
}

// ------------- Q[r] = b_q + dot(Wq[0:128], g) + dot(Wq[128:256], lv[r]) -------------
__global__ __launch_bounds__(NT) void final_kernel(
    const u16* __restrict__ lv, const float* __restrict__ g,
    const float* __restrict__ Wq, const float* __restrict__ bq,
    float* __restrict__ out)
{
  const int t = threadIdx.x, wave = t >> 6, l = t & 63;
  const float2 wg = *(const float2*)(Wq + 2 * l);
  const float2 wl = *(const float2*)(Wq + DD + 2 * l);
  const float2 gv = *(const float2*)(g + 2 * l);
  float q = wg.x * gv.x + wg.y * gv.y;
#pragma unroll
  for (int off = 32; off; off >>= 1) q += __shfl_down(q, off);
  const float qg = __shfl(q, 0) + bq[0];

  const int r0w = blockIdx.x * 64 + wave * 16;
#pragma unroll
  for (int i = 0; i < 16; ++i) {
    const int r = r0w + i;
    if (r >= NVV) break;
    u32 v = *(const u32*)(lv + (size_t)r * DD + 2 * l);
    float p = wl.x * b2f((u16)(v & 0xFFFF)) + wl.y * b2f((u16)(v >> 16));
#pragma unroll
    for (int off = 32; off; off >>= 1) p += __shfl_down(p, off);
    if (l == 0) out[r] = qg + p;
  }
}

extern "C" void kernel_launch(void* const* d_in, const int* in_sizes, int n_in,
                              void* d_out, int out_size, void* d_ws, size_t ws_size,
                              hipStream_t stream) {
  const float* x    = (const float*)d_in[0];
  const int*   vci  = (const int*)d_in[1];   // var_constr_index -> gathers from lc
  const int*   cvi  = (const int*)d_in[2];   // constr_var_index -> gathers from lv
  const float* W_iv = (const float*)d_in[3];
  const float* b_iv = (const float*)d_in[4];
  const float* W_ic = (const float*)d_in[5];
  const float* b_ic = (const float*)d_in[6];
  const float* W_v  = (const float*)d_in[7];
  const float* b_v  = (const float*)d_in[8];
  const float* W_c  = (const float*)d_in[9];
  const float* b_c  = (const float*)d_in[10];
  const float* W_q  = (const float*)d_in[11];
  const float* b_q  = (const float*)d_in[12];
  float* out = (float*)d_out;

  float* g = (float*)d_ws;
  u16* wbase = (u16*)((char*)d_ws + 512);
  const size_t nodef = (size_t)NVV * DD;
  u16* Wvsw  = wbase;
  u16* Wcsw  = Wvsw + (size_t)DD * INDIM;
  u16* Wivsw = Wcsw + (size_t)DD * INDIM;
  u16* Wicsw = Wivsw + (size_t)DD * FIN;
  u16* lv1   = Wicsw + (size_t)DD * FIN;      // bf16 final lv (it2 output)
  u8*  xvb8  = (u8*)(lv1 + nodef);            // fp8 feat
  u8*  xcb8  = xvb8 + (size_t)NVV * FIN;
  u8*  lv08  = xcb8 + (size_t)NCC * FIN;      // fp8 generations (all distinct)
  u8*  lc08  = lv08 + nodef;
  u8*  lv18  = lc08 + nodef;
  u8*  lc18  = lv18 + nodef;
  u8*  lv28  = lc18 + nodef;
  u8*  lc28  = lv28 + nodef;

  dim3 blk(NT);

  swizzle_all<<<41, blk, 0, stream>>>(W_v, W_c, W_iv, W_ic, Wvsw, Wcsw, Wivsw, Wicsw, g);
  init_fused<<<2 * GRID_HALF, blk, 0, stream>>>(x, Wivsw, Wicsw, b_iv, b_ic,
                                                lv08, lc08, xvb8, xcb8);

  // it0: C: gather lv08, self lc08 -> lc18 ; V: gather lc08, self lv08 -> lv18
  layer_merged<false><<<2 * GRID_HALF, blk, 0, stream>>>(
      lv08, lc08, xcb8, cvi, Wcsw, b_c, nullptr, lc18, NCC,
      lc08, lv08, xvb8, vci, Wvsw, b_v, nullptr, lv18, NVV, g, GRID_HALF);
  // it1: C: gather lv18, self lc18 -> lc28 ; V: gather lc18, self lv18 -> lv28
  layer_merged<false><<<2 * GRID_HALF, blk, 0, stream>>>(
      lv18, lc18, xcb8, cvi, Wcsw, b_c, nullptr, lc28, NCC,
      lc18, lv18, xvb8, vci, Wvsw, b_v, nullptr, lv28, NVV, g, GRID_HALF);
  // it2: V only: gather lc28, self lv28 -> lv1 (bf16) + g
  layer_merged<true><<<GRID_HALF, blk, 0, stream>>>(
      lc28, lv28, xvb8, vci, Wvsw, b_v, lv1, nullptr, NVV,  // unused C slot
      lc28, lv28, xvb8, vci, Wvsw, b_v, lv1, nullptr, NVV, g, 0);

  final_kernel<<<GRID_HALF, blk, 0, stream>>>(lv1, g, W_q, b_q, out);
}